// Round 1
// baseline (248.178 us; speedup 1.0000x reference)
//
#include <hip/hip_runtime.h>
#include <hip/hip_bf16.h>

typedef float f32x4 __attribute__((ext_vector_type(4)));
typedef short bf16x8 __attribute__((ext_vector_type(8)));

#define NPAIRS 16384
#define NROWS  32768
#define D      128
#define NCOL   512     // live gate cols (quad-interleaved: n' = 4*j + quad, j<128)
#define MROWS  32
#define FEW    5
#define NN     200
#define STEPS  4

// workspace offsets (bytes)
#define WS_WGP 0           // bf16 [12][512][32]  = 393216 B
#define WS_BP  393216      // f32  [512]
#define WS_SG  395264      // f32  [5][128]
#define WS_MS  397824      // f32  [128]

static __device__ __forceinline__ unsigned short f2bf(float f) {
  union { float f; unsigned u; } v; v.f = f;
  unsigned r = v.u + 0x7FFF + ((v.u >> 16) & 1);
  return (unsigned short)(r >> 16);
}
static __device__ __forceinline__ float bf2f(unsigned short h) {
  union { unsigned u; float f; } v; v.u = ((unsigned)h) << 16;
  return v.f;
}
static __device__ __forceinline__ float sigm(float x) {
  return 1.0f / (1.0f + __expf(-x));
}
static __device__ __forceinline__ float tanh_(float x) {
  float e = __expf(-2.0f * fabsf(x));
  float t = (1.0f - e) / (1.0f + e);
  return x >= 0.f ? t : -t;
}

// ---------------- prep: build quad-interleaved bf16 weight panel ----------------
// Wgp[ks][n'][ki] (ks<12, n'<512, ki<32), k = 32*ks+ki.
// n' = 4*j + quad  <->  gate row = 256*quad + j  (only j<128 kept: cols j>=128 are dead)
// value = k<128 ? W_ih[row][k] : W_hh[row][k-128]
__global__ void prep_w(const float* __restrict__ wih, const float* __restrict__ whh,
                       const float* __restrict__ bih, const float* __restrict__ bhh,
                       unsigned short* __restrict__ Wgp, float* __restrict__ bp) {
  int idx = blockIdx.x * 256 + threadIdx.x;
  if (idx < NCOL) {
    int j = idx >> 2, q = idx & 3;
    int rowg = q * 256 + j;
    bp[idx] = bih[rowg] + bhh[rowg];
  }
  if (idx >= 12 * NCOL * 32) return;
  int ks = idx >> 14;          // /(512*32)
  int n  = (idx >> 5) & 511;
  int ki = idx & 31;
  int k  = ks * 32 + ki;
  int j = n >> 2, q = n & 3;
  int rowg = q * 256 + j;
  float v = (k < 128) ? wih[rowg * 128 + k] : whh[rowg * 256 + (k - 128)];
  Wgp[idx] = f2bf(v);
}

// ---------------- support path (tiny): support_g (5x128) + mean_support ----------------
__global__ void support_kernel(
    const int* __restrict__ sp, const float* __restrict__ emb,
    const float* __restrict__ gw, const float* __restrict__ gb,
    const float* __restrict__ p1w, const float* __restrict__ p1b,
    const float* __restrict__ p2w, const float* __restrict__ p2b,
    const float* __restrict__ lng, const float* __restrict__ lnb,
    float* __restrict__ sg_out, float* __restrict__ ms_out) {
  __shared__ float S[FEW][256];
  __shared__ float sup[FEW][128];
  __shared__ float h1[FEW][256];
  __shared__ float xx[FEW][128];
  __shared__ float sgS[FEW][128];
  __shared__ float mv[FEW][2];
  int tid = threadIdx.x;
  // S[f][k] = sum_j concat[f][j][k]  (sum first, then one matvec — linearity)
  for (int i = tid; i < FEW * 256; i += 256) {
    int f = i >> 8, k = i & 255;
    int sel = k >> 7, kk = k & 127;
    float a = 0.f;
    for (int j = 0; j < NN; ++j) {
      int sym = sp[(f * NN + j) * 2 + sel];
      a += emb[(size_t)sym * D + kk];
    }
    S[f][k] = a;
  }
  __syncthreads();
  // support = tanh((S @ W.T + 200*b)/5)
  for (int i = tid; i < FEW * 128; i += 256) {
    int f = i >> 7, o = i & 127;
    float a = 0.f;
    for (int k = 0; k < 256; ++k) a += S[f][k] * gw[o * 256 + k];
    sup[f][o] = tanh_((a + 200.f * gb[o]) * 0.2f);
  }
  __syncthreads();
  for (int i = tid; i < FEW * 256; i += 256) {
    int f = i >> 8, p = i & 255;
    float a = p1b[p];
    for (int o = 0; o < 128; ++o) a += sup[f][o] * p1w[p * 128 + o];
    h1[f][p] = fmaxf(a, 0.f);
  }
  __syncthreads();
  for (int i = tid; i < FEW * 128; i += 256) {
    int f = i >> 7, o = i & 127;
    float a = p2b[o];
    for (int p = 0; p < 256; ++p) a += h1[f][p] * p2w[o * 256 + p];
    xx[f][o] = a + sup[f][o];
  }
  __syncthreads();
  if (tid < FEW) {
    float mu = 0.f;
    for (int k = 0; k < 128; ++k) mu += xx[tid][k];
    mu *= (1.f / 128.f);
    float var = 0.f;
    for (int k = 0; k < 128; ++k) { float dd = xx[tid][k] - mu; var += dd * dd; }
    var *= (1.f / 128.f);
    mv[tid][0] = mu;
    mv[tid][1] = rsqrtf(var + 1e-5f);
  }
  __syncthreads();
  for (int i = tid; i < FEW * 128; i += 256) {
    int f = i >> 7, o = i & 127;
    float v = lng[o] * (xx[f][o] - mv[f][0]) * mv[f][1] + lnb[o];
    sgS[f][o] = v;
    sg_out[i] = v;
  }
  __syncthreads();
  if (tid < 128) {
    float a = 0.f;
    for (int f = 0; f < FEW; ++f) a += sgS[f][tid];
    ms_out[tid] = a * 0.2f;
  }
}

// ---------------- fused query path: 4 LSTM+attn steps + final dot ----------------
// Block = 32 rows, 4 waves. Waves split the 512 live gate cols (128 col' = 32 j each).
// A (K=384) staged in LDS bf16: [q(128) | hq(128) | r(128)]. B streamed from L2,
// wave-coalesced (one n-tile fragment = contiguous 1 KB of Wgp).
__global__ __launch_bounds__(256, 2) void fused_query(
    const int* __restrict__ qp, const float* __restrict__ emb,
    const unsigned short* __restrict__ Wgp, const float* __restrict__ bp,
    const float* __restrict__ sgw, const float* __restrict__ msw,
    float* __restrict__ out) {
  __shared__ __align__(16) unsigned short sA[MROWS][392];  // 25088 B (pad: 784B rows, 16B-aligned)
  __shared__ unsigned short sC[MROWS][132];                // c state bf16, 8448 B
  __shared__ __align__(16) float sG[4][MROWS][36];         // per-wave gate bounce, 18432 B
  __shared__ float sSg[FEW][128];
  __shared__ float sMs[128];
  __shared__ __align__(16) float sBias[NCOL];

  int tid = threadIdx.x;
  int w = tid >> 6, lane = tid & 63;
  int l15 = lane & 15, l4 = lane >> 4;
  int row0 = blockIdx.x * MROWS;

  // gather q rows -> bf16 LDS (float4 loads)
  for (int i = tid; i < MROWS * 32; i += 256) {
    int r = i >> 5, c4 = i & 31;
    int sym = qp[row0 + r];
    f32x4 v = *(const f32x4*)(emb + (size_t)sym * D + c4 * 4);
    int k = c4 * 4;
    sA[r][k + 0] = f2bf(v[0]); sA[r][k + 1] = f2bf(v[1]);
    sA[r][k + 2] = f2bf(v[2]); sA[r][k + 3] = f2bf(v[3]);
  }
  for (int i = tid; i < MROWS * 256; i += 256) {  // h_r = 0
    int r = i >> 8, k = i & 255;
    sA[r][128 + k] = 0;
  }
  for (int i = tid; i < MROWS * 128; i += 256) sC[i >> 7][i & 127] = 0;
  for (int i = tid; i < FEW * 128; i += 256) sSg[i >> 7][i & 127] = sgw[i];
  if (tid < 128) sMs[tid] = msw[tid];
  for (int i = tid; i < NCOL; i += 256) sBias[i] = bp[i];
  __syncthreads();

  for (int s = 0; s < STEPS; ++s) {
    // ---- gates GEMM: rows 32 (2 M-tiles), wave's 128 col' (8 N-tiles), K=384 ----
    f32x4 acc[2][8];
#pragma unroll
    for (int mt = 0; mt < 2; ++mt)
#pragma unroll
      for (int nt = 0; nt < 8; ++nt) acc[mt][nt] = {0.f, 0.f, 0.f, 0.f};
    int ksmax = (s == 0) ? 4 : 12;  // step 0: h_r == 0, only q part contributes
    for (int ks = 0; ks < ksmax; ++ks) {
      bf16x8 a0 = *(const bf16x8*)&sA[l15][ks * 32 + l4 * 8];
      bf16x8 a1 = *(const bf16x8*)&sA[16 + l15][ks * 32 + l4 * 8];
      const unsigned short* wb =
          Wgp + (size_t)ks * (NCOL * 32) + (size_t)(w * 128 + l15) * 32 + l4 * 8;
#pragma unroll
      for (int nt = 0; nt < 8; ++nt) {
        bf16x8 b = *(const bf16x8*)(wb + nt * 512);  // nt*16 cols * 32 ki
        acc[0][nt] = __builtin_amdgcn_mfma_f32_16x16x32_bf16(a0, b, acc[0][nt], 0, 0, 0);
        acc[1][nt] = __builtin_amdgcn_mfma_f32_16x16x32_bf16(a1, b, acc[1][nt], 0, 0, 0);
      }
    }
    __syncthreads();  // all waves done reading old sA before hq overwrite

    // ---- elementwise LSTM (per-wave sG bounce; groups of 2 N-tiles = 8 j) ----
    int rr = lane >> 1;
    int jh = lane & 1;
#pragma unroll
    for (int g = 0; g < 4; ++g) {
#pragma unroll
      for (int hh = 0; hh < 2; ++hh) {
        int nt = 2 * g + hh;
#pragma unroll
        for (int mt = 0; mt < 2; ++mt)
#pragma unroll
          for (int e = 0; e < 4; ++e)
            sG[w][mt * 16 + l4 * 4 + e][hh * 16 + l15] = acc[mt][nt][e];
      }
      // same-wave LDS ops complete in order: no barrier needed
#pragma unroll
      for (int it = 0; it < 4; ++it) {
        int jl = it * 2 + jh;
        f32x4 gt = *(const f32x4*)&sG[w][rr][jl * 4];
        f32x4 bi = *(const f32x4*)&sBias[w * 128 + g * 32 + jl * 4];
        float gi = gt[0] + bi[0];
        float gf = gt[1] + bi[1];
        float gg = gt[2] + bi[2];
        float go = gt[3] + bi[3];
        int jg = w * 32 + g * 8 + jl;  // 0..127
        float c_old = bf2f(sC[rr][jg]);
        float c_new = sigm(gf) * c_old + sigm(gi) * tanh_(gg);
        sC[rr][jg] = f2bf(c_new);
        float hl = sigm(go) * tanh_(c_new);
        float hqv = bf2f(sA[rr][jg]) + hl;  // q + h_lstm
        sA[rr][128 + jg] = f2bf(hqv);
      }
    }
    __syncthreads();

    // ---- attention (skipped on last step: h_r is dead after it) ----
    if (s < STEPS - 1) {
      int arow = tid >> 3, part = tid & 7;  // 8 lanes per row, 16 k each
      float lg[FEW] = {0, 0, 0, 0, 0};
#pragma unroll
      for (int kk = 0; kk < 16; ++kk) {
        int k = part * 16 + kk;
        float hv = bf2f(sA[arow][128 + k]);
#pragma unroll
        for (int ss = 0; ss < FEW; ++ss) lg[ss] += hv * sSg[ss][k];
      }
#pragma unroll
      for (int off = 1; off < 8; off <<= 1)
#pragma unroll
        for (int ss = 0; ss < FEW; ++ss) lg[ss] += __shfl_xor(lg[ss], off, 64);
      float m = lg[0];
#pragma unroll
      for (int ss = 1; ss < FEW; ++ss) m = fmaxf(m, lg[ss]);
      float ev[FEW], tot = 0.f;
#pragma unroll
      for (int ss = 0; ss < FEW; ++ss) { ev[ss] = __expf(lg[ss] - m); tot += ev[ss]; }
      float inv = 1.0f / tot;
#pragma unroll
      for (int kk = 0; kk < 16; ++kk) {
        int k = part * 16 + kk;
        float rv = 0.f;
#pragma unroll
        for (int ss = 0; ss < FEW; ++ss) rv += ev[ss] * sSg[ss][k];
        sA[arow][256 + k] = f2bf(rv * inv);
      }
    }
    __syncthreads();
  }

  // ---- output: out[pair] = mean(hq[2p], hq[2p+1]) . mean_support ----
  int pair = tid >> 4, part = tid & 15;
  float accv = 0.f;
#pragma unroll
  for (int kk = 0; kk < 8; ++kk) {
    int k = part * 8 + kk;
    float h0 = bf2f(sA[2 * pair][128 + k]);
    float h1v = bf2f(sA[2 * pair + 1][128 + k]);
    accv += 0.5f * (h0 + h1v) * sMs[k];
  }
#pragma unroll
  for (int off = 1; off < 16; off <<= 1) accv += __shfl_xor(accv, off, 64);
  if (part == 0) out[blockIdx.x * 16 + pair] = accv;
}

extern "C" void kernel_launch(void* const* d_in, const int* in_sizes, int n_in,
                              void* d_out, int out_size, void* d_ws, size_t ws_size,
                              hipStream_t stream) {
  const int*   qp  = (const int*)d_in[0];
  const int*   sp  = (const int*)d_in[1];
  const float* emb = (const float*)d_in[2];
  const float* gw  = (const float*)d_in[3];
  const float* gb  = (const float*)d_in[4];
  const float* p1w = (const float*)d_in[5];
  const float* p1b = (const float*)d_in[6];
  const float* p2w = (const float*)d_in[7];
  const float* p2b = (const float*)d_in[8];
  const float* lng = (const float*)d_in[9];
  const float* lnb = (const float*)d_in[10];
  const float* wih = (const float*)d_in[11];
  const float* whh = (const float*)d_in[12];
  const float* bih = (const float*)d_in[13];
  const float* bhh = (const float*)d_in[14];
  char* ws = (char*)d_ws;
  unsigned short* Wgp = (unsigned short*)(ws + WS_WGP);
  float* bp = (float*)(ws + WS_BP);
  float* sg = (float*)(ws + WS_SG);
  float* ms = (float*)(ws + WS_MS);
  float* out = (float*)d_out;

  hipLaunchKernelGGL(prep_w, dim3(768), dim3(256), 0, stream, wih, whh, bih, bhh, Wgp, bp);
  hipLaunchKernelGGL(support_kernel, dim3(1), dim3(256), 0, stream,
                     sp, emb, gw, gb, p1w, p1b, p2w, p2b, lng, lnb, sg, ms);
  hipLaunchKernelGGL(fused_query, dim3(NROWS / MROWS), dim3(256), 0, stream,
                     qp, emb, Wgp, bp, sg, ms, out);
}

// Round 2
// 185.084 us; speedup vs baseline: 1.3409x; 1.3409x over previous
//
#include <hip/hip_runtime.h>
#include <hip/hip_bf16.h>

typedef float f32x4 __attribute__((ext_vector_type(4)));
typedef short bf16x8 __attribute__((ext_vector_type(8)));

#define NPAIRS 16384
#define NROWS  32768
#define D      128
#define NCOL   512     // live gate cols (quad-interleaved: n' = 4*j + quad, j<128)
#define MROWS  32
#define FEW    5
#define NN     200
#define STEPS  4
#define JCH    25      // j-chunks for support gather (8 neighbors each)

// workspace offsets (bytes)
#define WS_WGP  0           // bf16 [12][512][32]  = 393216 B
#define WS_BP   393216      // f32  [512]
#define WS_SG   395264      // f32  [5][128]
#define WS_MS   397824      // f32  [128]
#define WS_PART 398336      // f32  [5*25][256] = 128000 B

static __device__ __forceinline__ unsigned short f2bf(float f) {
  union { float f; unsigned u; } v; v.f = f;
  unsigned r = v.u + 0x7FFF + ((v.u >> 16) & 1);
  return (unsigned short)(r >> 16);
}
static __device__ __forceinline__ float bf2f(unsigned short h) {
  union { unsigned u; float f; } v; v.u = ((unsigned)h) << 16;
  return v.f;
}
static __device__ __forceinline__ float sigm(float x) {
  return 1.0f / (1.0f + __expf(-x));
}
static __device__ __forceinline__ float tanh_(float x) {
  float e = __expf(-2.0f * fabsf(x));
  float t = (1.0f - e) / (1.0f + e);
  return x >= 0.f ? t : -t;
}

// ---------------- prep: build quad-interleaved bf16 weight panel ----------------
__global__ void prep_w(const float* __restrict__ wih, const float* __restrict__ whh,
                       const float* __restrict__ bih, const float* __restrict__ bhh,
                       unsigned short* __restrict__ Wgp, float* __restrict__ bp) {
  int idx = blockIdx.x * 256 + threadIdx.x;
  if (idx < NCOL) {
    int j = idx >> 2, q = idx & 3;
    int rowg = q * 256 + j;
    bp[idx] = bih[rowg] + bhh[rowg];
  }
  if (idx >= 12 * NCOL * 32) return;
  int ks = idx >> 14;          // /(512*32)
  int n  = (idx >> 5) & 511;
  int ki = idx & 31;
  int k  = ks * 32 + ki;
  int j = n >> 2, q = n & 3;
  int rowg = q * 256 + j;
  float v = (k < 128) ? wih[rowg * 128 + k] : whh[rowg * 256 + (k - 128)];
  Wgp[idx] = f2bf(v);
}

// ---------------- support gather: parallel over (f, j-chunk) ----------------
// part[(f*JCH+cj)*256 + k] = sum_{j in chunk} emb[sp[f][j][k>>7]][k&127]
__global__ void support_gather(const int* __restrict__ sp, const float* __restrict__ emb,
                               float* __restrict__ part) {
  int f = blockIdx.x, cj = blockIdx.y;
  int k = threadIdx.x;
  int sel = k >> 7, kk = k & 127;
  float a = 0.f;
#pragma unroll
  for (int jj = 0; jj < 8; ++jj) {
    int j = cj * 8 + jj;
    int sym = sp[(f * NN + j) * 2 + sel];
    a += emb[(size_t)sym * D + kk];
  }
  part[(f * JCH + cj) * 256 + k] = a;
}

// ---------------- support stage 2: reduce partials + MLP + LN ----------------
__global__ void support_kernel(
    const float* __restrict__ part,
    const float* __restrict__ gw, const float* __restrict__ gb,
    const float* __restrict__ p1w, const float* __restrict__ p1b,
    const float* __restrict__ p2w, const float* __restrict__ p2b,
    const float* __restrict__ lng, const float* __restrict__ lnb,
    float* __restrict__ sg_out, float* __restrict__ ms_out) {
  __shared__ float S[FEW][256];
  __shared__ float sup[FEW][128];
  __shared__ float h1[FEW][256];
  __shared__ float xx[FEW][128];
  __shared__ float sgS[FEW][128];
  __shared__ float mv[FEW][2];
  int tid = threadIdx.x;
  for (int i = tid; i < FEW * 256; i += 256) {
    int f = i >> 8, k = i & 255;
    float a = 0.f;
#pragma unroll
    for (int c = 0; c < JCH; ++c) a += part[(f * JCH + c) * 256 + k];
    S[f][k] = a;
  }
  __syncthreads();
  // support = tanh((S @ W.T + 200*b)/5)
  for (int i = tid; i < FEW * 128; i += 256) {
    int f = i >> 7, o = i & 127;
    float a = 0.f;
    for (int k = 0; k < 256; ++k) a += S[f][k] * gw[o * 256 + k];
    sup[f][o] = tanh_((a + 200.f * gb[o]) * 0.2f);
  }
  __syncthreads();
  for (int i = tid; i < FEW * 256; i += 256) {
    int f = i >> 8, p = i & 255;
    float a = p1b[p];
    for (int o = 0; o < 128; ++o) a += sup[f][o] * p1w[p * 128 + o];
    h1[f][p] = fmaxf(a, 0.f);
  }
  __syncthreads();
  for (int i = tid; i < FEW * 128; i += 256) {
    int f = i >> 7, o = i & 127;
    float a = p2b[o];
    for (int p = 0; p < 256; ++p) a += h1[f][p] * p2w[o * 256 + p];
    xx[f][o] = a + sup[f][o];
  }
  __syncthreads();
  if (tid < FEW) {
    float mu = 0.f;
    for (int k = 0; k < 128; ++k) mu += xx[tid][k];
    mu *= (1.f / 128.f);
    float var = 0.f;
    for (int k = 0; k < 128; ++k) { float dd = xx[tid][k] - mu; var += dd * dd; }
    var *= (1.f / 128.f);
    mv[tid][0] = mu;
    mv[tid][1] = rsqrtf(var + 1e-5f);
  }
  __syncthreads();
  for (int i = tid; i < FEW * 128; i += 256) {
    int f = i >> 7, o = i & 127;
    float v = lng[o] * (xx[f][o] - mv[f][0]) * mv[f][1] + lnb[o];
    sgS[f][o] = v;
    sg_out[i] = v;
  }
  __syncthreads();
  if (tid < 128) {
    float a = 0.f;
    for (int f = 0; f < FEW; ++f) a += sgS[f][tid];
    ms_out[tid] = a * 0.2f;
  }
}

// ---------------- fused query path: 4 LSTM+attn steps + final dot ----------------
__global__ __launch_bounds__(256, 2) void fused_query(
    const int* __restrict__ qp, const float* __restrict__ emb,
    const unsigned short* __restrict__ Wgp, const float* __restrict__ bp,
    const float* __restrict__ sgw, const float* __restrict__ msw,
    float* __restrict__ out) {
  __shared__ __align__(16) unsigned short sA[MROWS][392];  // 25088 B
  __shared__ unsigned short sC[MROWS][132];                // c state bf16
  __shared__ __align__(16) float sG[4][MROWS][36];         // per-wave gate bounce
  __shared__ float sSg[FEW][128];
  __shared__ float sMs[128];
  __shared__ __align__(16) float sBias[NCOL];

  int tid = threadIdx.x;
  int w = tid >> 6, lane = tid & 63;
  int l15 = lane & 15, l4 = lane >> 4;
  int row0 = blockIdx.x * MROWS;

  // gather q rows -> bf16 LDS (float4 loads)
  for (int i = tid; i < MROWS * 32; i += 256) {
    int r = i >> 5, c4 = i & 31;
    int sym = qp[row0 + r];
    f32x4 v = *(const f32x4*)(emb + (size_t)sym * D + c4 * 4);
    int k = c4 * 4;
    sA[r][k + 0] = f2bf(v[0]); sA[r][k + 1] = f2bf(v[1]);
    sA[r][k + 2] = f2bf(v[2]); sA[r][k + 3] = f2bf(v[3]);
  }
  for (int i = tid; i < MROWS * 256; i += 256) {  // h_r = 0
    int r = i >> 8, k = i & 255;
    sA[r][128 + k] = 0;
  }
  for (int i = tid; i < MROWS * 128; i += 256) sC[i >> 7][i & 127] = 0;
  for (int i = tid; i < FEW * 128; i += 256) sSg[i >> 7][i & 127] = sgw[i];
  if (tid < 128) sMs[tid] = msw[tid];
  for (int i = tid; i < NCOL; i += 256) sBias[i] = bp[i];
  __syncthreads();

  for (int s = 0; s < STEPS; ++s) {
    // ---- gates GEMM: rows 32 (2 M-tiles), wave's 128 col' (8 N-tiles), K=384 ----
    f32x4 acc[2][8];
#pragma unroll
    for (int mt = 0; mt < 2; ++mt)
#pragma unroll
      for (int nt = 0; nt < 8; ++nt) acc[mt][nt] = {0.f, 0.f, 0.f, 0.f};
    int ksmax = (s == 0) ? 4 : 12;  // step 0: h_r == 0, only q part contributes
    for (int ks = 0; ks < ksmax; ++ks) {
      bf16x8 a0 = *(const bf16x8*)&sA[l15][ks * 32 + l4 * 8];
      bf16x8 a1 = *(const bf16x8*)&sA[16 + l15][ks * 32 + l4 * 8];
      const unsigned short* wb =
          Wgp + (size_t)ks * (NCOL * 32) + (size_t)(w * 128 + l15) * 32 + l4 * 8;
#pragma unroll
      for (int nt = 0; nt < 8; ++nt) {
        bf16x8 b = *(const bf16x8*)(wb + nt * 512);
        acc[0][nt] = __builtin_amdgcn_mfma_f32_16x16x32_bf16(a0, b, acc[0][nt], 0, 0, 0);
        acc[1][nt] = __builtin_amdgcn_mfma_f32_16x16x32_bf16(a1, b, acc[1][nt], 0, 0, 0);
      }
    }
    __syncthreads();  // all waves done reading old sA before hq overwrite

    // ---- elementwise LSTM (per-wave sG bounce; groups of 2 N-tiles = 8 j) ----
    int rr = lane >> 1;
    int jh = lane & 1;
#pragma unroll
    for (int g = 0; g < 4; ++g) {
#pragma unroll
      for (int hh = 0; hh < 2; ++hh) {
        int nt = 2 * g + hh;
#pragma unroll
        for (int mt = 0; mt < 2; ++mt)
#pragma unroll
          for (int e = 0; e < 4; ++e)
            sG[w][mt * 16 + l4 * 4 + e][hh * 16 + l15] = acc[mt][nt][e];
      }
#pragma unroll
      for (int it = 0; it < 4; ++it) {
        int jl = it * 2 + jh;
        f32x4 gt = *(const f32x4*)&sG[w][rr][jl * 4];
        f32x4 bi = *(const f32x4*)&sBias[w * 128 + g * 32 + jl * 4];
        float gi = gt[0] + bi[0];
        float gf = gt[1] + bi[1];
        float gg = gt[2] + bi[2];
        float go = gt[3] + bi[3];
        int jg = w * 32 + g * 8 + jl;  // 0..127
        float c_old = bf2f(sC[rr][jg]);
        float c_new = sigm(gf) * c_old + sigm(gi) * tanh_(gg);
        sC[rr][jg] = f2bf(c_new);
        float hl = sigm(go) * tanh_(c_new);
        float hqv = bf2f(sA[rr][jg]) + hl;  // q + h_lstm
        sA[rr][128 + jg] = f2bf(hqv);
      }
    }
    __syncthreads();

    // ---- attention (skipped on last step: h_r is dead after it) ----
    if (s < STEPS - 1) {
      int arow = tid >> 3, part = tid & 7;  // 8 lanes per row, 16 k each
      float lg[FEW] = {0, 0, 0, 0, 0};
#pragma unroll
      for (int kk = 0; kk < 16; ++kk) {
        int k = part * 16 + kk;
        float hv = bf2f(sA[arow][128 + k]);
#pragma unroll
        for (int ss = 0; ss < FEW; ++ss) lg[ss] += hv * sSg[ss][k];
      }
#pragma unroll
      for (int off = 1; off < 8; off <<= 1)
#pragma unroll
        for (int ss = 0; ss < FEW; ++ss) lg[ss] += __shfl_xor(lg[ss], off, 64);
      float m = lg[0];
#pragma unroll
      for (int ss = 1; ss < FEW; ++ss) m = fmaxf(m, lg[ss]);
      float ev[FEW], tot = 0.f;
#pragma unroll
      for (int ss = 0; ss < FEW; ++ss) { ev[ss] = __expf(lg[ss] - m); tot += ev[ss]; }
      float inv = 1.0f / tot;
#pragma unroll
      for (int kk = 0; kk < 16; ++kk) {
        int k = part * 16 + kk;
        float rv = 0.f;
#pragma unroll
        for (int ss = 0; ss < FEW; ++ss) rv += ev[ss] * sSg[ss][k];
        sA[arow][256 + k] = f2bf(rv * inv);
      }
    }
    __syncthreads();
  }

  // ---- output: out[pair] = mean(hq[2p], hq[2p+1]) . mean_support ----
  int pair = tid >> 4, part = tid & 15;
  float accv = 0.f;
#pragma unroll
  for (int kk = 0; kk < 8; ++kk) {
    int k = part * 8 + kk;
    float h0 = bf2f(sA[2 * pair][128 + k]);
    float h1v = bf2f(sA[2 * pair + 1][128 + k]);
    accv += 0.5f * (h0 + h1v) * sMs[k];
  }
#pragma unroll
  for (int off = 1; off < 16; off <<= 1) accv += __shfl_xor(accv, off, 64);
  if (part == 0) out[blockIdx.x * 16 + pair] = accv;
}

extern "C" void kernel_launch(void* const* d_in, const int* in_sizes, int n_in,
                              void* d_out, int out_size, void* d_ws, size_t ws_size,
                              hipStream_t stream) {
  const int*   qp  = (const int*)d_in[0];
  const int*   sp  = (const int*)d_in[1];
  const float* emb = (const float*)d_in[2];
  const float* gw  = (const float*)d_in[3];
  const float* gb  = (const float*)d_in[4];
  const float* p1w = (const float*)d_in[5];
  const float* p1b = (const float*)d_in[6];
  const float* p2w = (const float*)d_in[7];
  const float* p2b = (const float*)d_in[8];
  const float* lng = (const float*)d_in[9];
  const float* lnb = (const float*)d_in[10];
  const float* wih = (const float*)d_in[11];
  const float* whh = (const float*)d_in[12];
  const float* bih = (const float*)d_in[13];
  const float* bhh = (const float*)d_in[14];
  char* ws = (char*)d_ws;
  unsigned short* Wgp = (unsigned short*)(ws + WS_WGP);
  float* bp   = (float*)(ws + WS_BP);
  float* sg   = (float*)(ws + WS_SG);
  float* ms   = (float*)(ws + WS_MS);
  float* part = (float*)(ws + WS_PART);
  float* out  = (float*)d_out;

  hipLaunchKernelGGL(prep_w, dim3(768), dim3(256), 0, stream, wih, whh, bih, bhh, Wgp, bp);
  hipLaunchKernelGGL(support_gather, dim3(FEW, JCH), dim3(256), 0, stream, sp, emb, part);
  hipLaunchKernelGGL(support_kernel, dim3(1), dim3(256), 0, stream,
                     part, gw, gb, p1w, p1b, p2w, p2b, lng, lnb, sg, ms);
  hipLaunchKernelGGL(fused_query, dim3(NROWS / MROWS), dim3(256), 0, stream,
                     qp, emb, Wgp, bp, sg, ms, out);
}

// Round 3
// 155.461 us; speedup vs baseline: 1.5964x; 1.1906x over previous
//
#include <hip/hip_runtime.h>
#include <hip/hip_bf16.h>

typedef float f32x4 __attribute__((ext_vector_type(4)));
typedef short bf16x8 __attribute__((ext_vector_type(8)));

#define NPAIRS 16384
#define NROWS  32768
#define D      128
#define NCOL   512     // live gate cols (quad-interleaved: n' = 4*j + quad, j<128)
#define MROWS  64
#define FEW    5
#define NN     200
#define STEPS  4
#define JCH    25      // j-chunks for support gather (8 neighbors each)

// workspace offsets (bytes)
#define WS_WGP  0           // bf16 [12][512][32]  = 393216 B
#define WS_BP   393216      // f32  [512]
#define WS_SG   395264      // f32  [5][128]
#define WS_MS   397824      // f32  [128]
#define WS_PART 398336      // f32  [5*25][256] = 128000 B

static __device__ __forceinline__ unsigned short f2bf(float f) {
  union { float f; unsigned u; } v; v.f = f;
  unsigned r = v.u + 0x7FFF + ((v.u >> 16) & 1);
  return (unsigned short)(r >> 16);
}
static __device__ __forceinline__ float bf2f(unsigned short h) {
  union { unsigned u; float f; } v; v.u = ((unsigned)h) << 16;
  return v.f;
}
static __device__ __forceinline__ float sigm(float x) {
  return 1.0f / (1.0f + __expf(-x));
}
static __device__ __forceinline__ float tanh_(float x) {
  float e = __expf(-2.0f * fabsf(x));
  float t = (1.0f - e) / (1.0f + e);
  return x >= 0.f ? t : -t;
}

// ---------------- prep: build quad-interleaved bf16 weight panel ----------------
// Wgp[ks][n'][ki] (ks<12, n'<512, ki<32), k = 32*ks+ki.
// n' = 4*j + quad  <->  gate row = 256*quad + j  (cols j>=128 are dead)
__global__ void prep_w(const float* __restrict__ wih, const float* __restrict__ whh,
                       const float* __restrict__ bih, const float* __restrict__ bhh,
                       unsigned short* __restrict__ Wgp, float* __restrict__ bp) {
  int idx = blockIdx.x * 256 + threadIdx.x;
  if (idx < NCOL) {
    int j = idx >> 2, q = idx & 3;
    int rowg = q * 256 + j;
    bp[idx] = bih[rowg] + bhh[rowg];
  }
  if (idx >= 12 * NCOL * 32) return;
  int ks = idx >> 14;          // /(512*32)
  int n  = (idx >> 5) & 511;
  int ki = idx & 31;
  int k  = ks * 32 + ki;
  int j = n >> 2, q = n & 3;
  int rowg = q * 256 + j;
  float v = (k < 128) ? wih[rowg * 128 + k] : whh[rowg * 256 + (k - 128)];
  Wgp[idx] = f2bf(v);
}

// ---------------- support gather: parallel over (f, j-chunk) ----------------
__global__ void support_gather(const int* __restrict__ sp, const float* __restrict__ emb,
                               float* __restrict__ part) {
  int f = blockIdx.x, cj = blockIdx.y;
  int k = threadIdx.x;
  int sel = k >> 7, kk = k & 127;
  float a = 0.f;
#pragma unroll
  for (int jj = 0; jj < 8; ++jj) {
    int j = cj * 8 + jj;
    int sym = sp[(f * NN + j) * 2 + sel];
    a += emb[(size_t)sym * D + kk];
  }
  part[(f * JCH + cj) * 256 + k] = a;
}

// ---------------- support stage 2: reduce partials + MLP + LN ----------------
__global__ void support_kernel(
    const float* __restrict__ part,
    const float* __restrict__ gw, const float* __restrict__ gb,
    const float* __restrict__ p1w, const float* __restrict__ p1b,
    const float* __restrict__ p2w, const float* __restrict__ p2b,
    const float* __restrict__ lng, const float* __restrict__ lnb,
    float* __restrict__ sg_out, float* __restrict__ ms_out) {
  __shared__ float S[FEW][256];
  __shared__ float sup[FEW][128];
  __shared__ float h1[FEW][256];
  __shared__ float xx[FEW][128];
  __shared__ float sgS[FEW][128];
  __shared__ float mv[FEW][2];
  int tid = threadIdx.x;
  for (int i = tid; i < FEW * 256; i += 256) {
    int f = i >> 8, k = i & 255;
    float a = 0.f;
#pragma unroll
    for (int c = 0; c < JCH; ++c) a += part[(f * JCH + c) * 256 + k];
    S[f][k] = a;
  }
  __syncthreads();
  for (int i = tid; i < FEW * 128; i += 256) {
    int f = i >> 7, o = i & 127;
    float a = 0.f;
    for (int k = 0; k < 256; ++k) a += S[f][k] * gw[o * 256 + k];
    sup[f][o] = tanh_((a + 200.f * gb[o]) * 0.2f);
  }
  __syncthreads();
  for (int i = tid; i < FEW * 256; i += 256) {
    int f = i >> 8, p = i & 255;
    float a = p1b[p];
    for (int o = 0; o < 128; ++o) a += sup[f][o] * p1w[p * 128 + o];
    h1[f][p] = fmaxf(a, 0.f);
  }
  __syncthreads();
  for (int i = tid; i < FEW * 128; i += 256) {
    int f = i >> 7, o = i & 127;
    float a = p2b[o];
    for (int p = 0; p < 256; ++p) a += h1[f][p] * p2w[o * 256 + p];
    xx[f][o] = a + sup[f][o];
  }
  __syncthreads();
  if (tid < FEW) {
    float mu = 0.f;
    for (int k = 0; k < 128; ++k) mu += xx[tid][k];
    mu *= (1.f / 128.f);
    float var = 0.f;
    for (int k = 0; k < 128; ++k) { float dd = xx[tid][k] - mu; var += dd * dd; }
    var *= (1.f / 128.f);
    mv[tid][0] = mu;
    mv[tid][1] = rsqrtf(var + 1e-5f);
  }
  __syncthreads();
  for (int i = tid; i < FEW * 128; i += 256) {
    int f = i >> 7, o = i & 127;
    float v = lng[o] * (xx[f][o] - mv[f][0]) * mv[f][1] + lnb[o];
    sgS[f][o] = v;
    sg_out[i] = v;
  }
  __syncthreads();
  if (tid < 128) {
    float a = 0.f;
    for (int f = 0; f < FEW; ++f) a += sgS[f][tid];
    ms_out[tid] = a * 0.2f;
  }
}

// ---------------- fused query path: 4 LSTM+attn steps + final dot ----------------
// Block = 64 rows, 8 waves (512 thr). Waves split the 512 live gate cols: 64 each.
// SWAPPED MFMA: D = mfma(W_frag, A_frag) -> acc[gt][bt][e] = gates[n'=w*64+gt*16+l4*4+e][row=bt*16+l15]
// With quad-interleave n'=4j+q: e IS the quad index -> f32x4 acc = (i,f,g,o) for
// (row = bt*16+l15, j = 16w+gt*4+l4). No transpose/bounce needed.
__global__ __launch_bounds__(512, 4) void fused_query(
    const int* __restrict__ qp, const float* __restrict__ emb,
    const unsigned short* __restrict__ Wgp, const float* __restrict__ bp,
    const float* __restrict__ sgw, const float* __restrict__ msw,
    float* __restrict__ out) {
  __shared__ __align__(16) unsigned short sA[MROWS][392];  // q|hq|r, 50176 B
  __shared__ unsigned short sC[MROWS][130];                // c state bf16, 16640 B
  __shared__ float sSg[FEW][128];
  __shared__ float sMs[128];
  __shared__ __align__(16) float sBias[NCOL];

  int tid = threadIdx.x;
  int w = tid >> 6, lane = tid & 63;
  int l15 = lane & 15, l4 = lane >> 4;
  int w16 = w * 16;
  int row0 = blockIdx.x * MROWS;

  // gather q rows -> bf16 LDS (float4 loads)
  for (int i = tid; i < MROWS * 32; i += 512) {
    int r = i >> 5, c4 = i & 31;
    int sym = qp[row0 + r];
    f32x4 v = *(const f32x4*)(emb + (size_t)sym * D + c4 * 4);
    int k = c4 * 4;
    sA[r][k + 0] = f2bf(v[0]); sA[r][k + 1] = f2bf(v[1]);
    sA[r][k + 2] = f2bf(v[2]); sA[r][k + 3] = f2bf(v[3]);
  }
  for (int i = tid; i < MROWS * 256; i += 512) sA[i >> 8][128 + (i & 255)] = 0;
  for (int i = tid; i < MROWS * 128; i += 512) sC[i >> 7][i & 127] = 0;
  for (int i = tid; i < FEW * 128; i += 512) sSg[i >> 7][i & 127] = sgw[i];
  if (tid < 128) sMs[tid] = msw[tid];
  if (tid < NCOL) sBias[tid] = bp[tid];
  __syncthreads();

  const unsigned short* wptr = Wgp + (size_t)(w * 64 + l15) * 32 + l4 * 8;

  for (int s = 0; s < STEPS; ++s) {
    // ---- gates GEMM: 4 gate-tiles x 4 row-tiles, K=384 ----
    f32x4 acc[4][4];
#pragma unroll
    for (int gt = 0; gt < 4; ++gt)
#pragma unroll
      for (int bt = 0; bt < 4; ++bt) acc[gt][bt] = {0.f, 0.f, 0.f, 0.f};
    int ksmax = (s == 0) ? 4 : 12;  // step 0: h_r == 0
    for (int ks = 0; ks < ksmax; ++ks) {
      const unsigned short* wk = wptr + ks * (NCOL * 32);
      bf16x8 bfrag[4];
#pragma unroll
      for (int gt = 0; gt < 4; ++gt) bfrag[gt] = *(const bf16x8*)(wk + gt * 512);
      bf16x8 afrag[4];
#pragma unroll
      for (int bt = 0; bt < 4; ++bt)
        afrag[bt] = *(const bf16x8*)&sA[bt * 16 + l15][ks * 32 + l4 * 8];
#pragma unroll
      for (int gt = 0; gt < 4; ++gt)
#pragma unroll
        for (int bt = 0; bt < 4; ++bt)
          acc[gt][bt] = __builtin_amdgcn_mfma_f32_16x16x32_bf16(
              bfrag[gt], afrag[bt], acc[gt][bt], 0, 0, 0);
    }
    __syncthreads();  // all GEMM reads of sA done before hq overwrite

    // ---- elementwise LSTM: acc f32x4 IS the (i,f,g,o) quadruple ----
#pragma unroll
    for (int gt = 0; gt < 4; ++gt) {
      int j = w16 + gt * 4 + l4;
      f32x4 bi = *(const f32x4*)&sBias[4 * j];  // uniform over l15 -> broadcast
#pragma unroll
      for (int bt = 0; bt < 4; ++bt) {
        f32x4 g = acc[gt][bt];
        float gi = g[0] + bi[0];
        float gf = g[1] + bi[1];
        float gg = g[2] + bi[2];
        float go = g[3] + bi[3];
        int row = bt * 16 + l15;
        float c_old = bf2f(sC[row][j]);
        float c_new = sigm(gf) * c_old + sigm(gi) * tanh_(gg);
        sC[row][j] = f2bf(c_new);
        float hl = sigm(go) * tanh_(c_new);
        float hqv = bf2f(sA[row][j]) + hl;  // q + h_lstm
        sA[row][128 + j] = f2bf(hqv);
      }
    }
    __syncthreads();

    // ---- attention (skipped on last step: h_r dead after it) ----
    if (s < STEPS - 1) {
      int arow = tid >> 3, part = tid & 7;  // 8 lanes per row, 16 k each
      float lg[FEW] = {0, 0, 0, 0, 0};
#pragma unroll
      for (int kk = 0; kk < 16; ++kk) {
        int k = part * 16 + kk;
        float hv = bf2f(sA[arow][128 + k]);
#pragma unroll
        for (int ss = 0; ss < FEW; ++ss) lg[ss] += hv * sSg[ss][k];
      }
#pragma unroll
      for (int off = 1; off < 8; off <<= 1)
#pragma unroll
        for (int ss = 0; ss < FEW; ++ss) lg[ss] += __shfl_xor(lg[ss], off, 64);
      float m = lg[0];
#pragma unroll
      for (int ss = 1; ss < FEW; ++ss) m = fmaxf(m, lg[ss]);
      float ev[FEW], tot = 0.f;
#pragma unroll
      for (int ss = 0; ss < FEW; ++ss) { ev[ss] = __expf(lg[ss] - m); tot += ev[ss]; }
      float inv = 1.0f / tot;
#pragma unroll
      for (int kk = 0; kk < 16; ++kk) {
        int k = part * 16 + kk;
        float rv = 0.f;
#pragma unroll
        for (int ss = 0; ss < FEW; ++ss) rv += ev[ss] * sSg[ss][k];
        sA[arow][256 + k] = f2bf(rv * inv);
      }
      __syncthreads();
    }
  }

  // ---- output: out[pair] = mean(hq[2p], hq[2p+1]) . mean_support ----
  int pair = tid >> 4, part = tid & 15;  // 32 pairs, 16 lanes each, 8 k per lane
  float accv = 0.f;
#pragma unroll
  for (int kk = 0; kk < 8; ++kk) {
    int k = part * 8 + kk;
    float h0 = bf2f(sA[2 * pair][128 + k]);
    float h1v = bf2f(sA[2 * pair + 1][128 + k]);
    accv += 0.5f * (h0 + h1v) * sMs[k];
  }
#pragma unroll
  for (int off = 1; off < 16; off <<= 1) accv += __shfl_xor(accv, off, 64);
  if (part == 0) out[blockIdx.x * 32 + pair] = accv;
}

extern "C" void kernel_launch(void* const* d_in, const int* in_sizes, int n_in,
                              void* d_out, int out_size, void* d_ws, size_t ws_size,
                              hipStream_t stream) {
  const int*   qp  = (const int*)d_in[0];
  const int*   sp  = (const int*)d_in[1];
  const float* emb = (const float*)d_in[2];
  const float* gw  = (const float*)d_in[3];
  const float* gb  = (const float*)d_in[4];
  const float* p1w = (const float*)d_in[5];
  const float* p1b = (const float*)d_in[6];
  const float* p2w = (const float*)d_in[7];
  const float* p2b = (const float*)d_in[8];
  const float* lng = (const float*)d_in[9];
  const float* lnb = (const float*)d_in[10];
  const float* wih = (const float*)d_in[11];
  const float* whh = (const float*)d_in[12];
  const float* bih = (const float*)d_in[13];
  const float* bhh = (const float*)d_in[14];
  char* ws = (char*)d_ws;
  unsigned short* Wgp = (unsigned short*)(ws + WS_WGP);
  float* bp   = (float*)(ws + WS_BP);
  float* sg   = (float*)(ws + WS_SG);
  float* ms   = (float*)(ws + WS_MS);
  float* part = (float*)(ws + WS_PART);
  float* out  = (float*)d_out;

  hipLaunchKernelGGL(prep_w, dim3(768), dim3(256), 0, stream, wih, whh, bih, bhh, Wgp, bp);
  hipLaunchKernelGGL(support_gather, dim3(FEW, JCH), dim3(256), 0, stream, sp, emb, part);
  hipLaunchKernelGGL(support_kernel, dim3(1), dim3(256), 0, stream,
                     part, gw, gb, p1w, p1b, p2w, p2b, lng, lnb, sg, ms);
  hipLaunchKernelGGL(fused_query, dim3(NROWS / MROWS), dim3(512), 0, stream,
                     qp, emb, Wgp, bp, sg, ms, out);
}